// Round 11
// baseline (1693.512 us; speedup 1.0000x reference)
//
#include <hip/hip_runtime.h>
#include <hip/hip_fp16.h>
#include <math.h>

#define Q 8
#define TPB 256
#define WPB (TPB / 64)     // waves per block
#define SCAN_T 1024

struct alignas(16) H8 { __half h[8]; };

// ---------- helpers ----------

__device__ __forceinline__ float fast_rcp(float x) {
  return __builtin_amdgcn_rcpf(x);
}

__device__ __forceinline__ void load8(const float* __restrict__ p, float r[Q]) {
  const float4* p4 = reinterpret_cast<const float4*>(p);
  float4 a = p4[0], b = p4[1];
  r[0]=a.x; r[1]=a.y; r[2]=a.z; r[3]=a.w;
  r[4]=b.x; r[5]=b.y; r[6]=b.z; r[7]=b.w;
}

__device__ __forceinline__ void store8h(__half* __restrict__ p, const float r[Q]) {
  H8 t;
#pragma unroll
  for (int j=0;j<Q;j++) t.h[j] = __float2half(r[j]);
  *reinterpret_cast<H8*>(p) = t;
}

__device__ __forceinline__ float wave_sum(float x) {
  x += __shfl_down(x, 32);
  x += __shfl_down(x, 16);
  x += __shfl_down(x, 8);
  x += __shfl_down(x, 4);
  x += __shfl_down(x, 2);
  x += __shfl_down(x, 1);
  return x;
}

__device__ __forceinline__ void block_reduce_atomic(float x, float* target, float* lds) {
  float w = wave_sum(x);
  const int lane = threadIdx.x & 63, wid = threadIdx.x >> 6;
  if (lane == 0) lds[wid] = w;
  __syncthreads();
  if (threadIdx.x == 0) {
    float t = 0.f;
#pragma unroll
    for (int i = 0; i < WPB; i++) t += lds[i];
    atomicAdd(target, t);
  }
  __syncthreads();
}

__device__ __forceinline__ float sum8_lanes(float x) {
  x += __shfl_xor(x, 1);
  x += __shfl_xor(x, 2);
  x += __shfl_xor(x, 4);
  return x;
}

// ---------- CSR build ----------

// count + local rank; 4 edges per thread (measured-best variant)
__global__ void k_count_pos(const int* __restrict__ dst, int* __restrict__ cnt,
                            int* __restrict__ pos, int E) {
  int i0 = (blockIdx.x * TPB + threadIdx.x) * 4;
  if (i0 + 3 < E) {
    int4 d = *reinterpret_cast<const int4*>(dst + i0);
    int p0 = atomicAdd(&cnt[d.x], 1);
    int p1 = atomicAdd(&cnt[d.y], 1);
    int p2 = atomicAdd(&cnt[d.z], 1);
    int p3 = atomicAdd(&cnt[d.w], 1);
    *reinterpret_cast<int4*>(pos + i0) = make_int4(p0, p1, p2, p3);
  } else {
    for (int e = i0; e < E; e++) pos[e] = atomicAdd(&cnt[dst[e]], 1);
  }
}

__global__ void k_scan1(const int* __restrict__ cnt, int* __restrict__ row_ptr,
                        int* __restrict__ bsum, int N) {
  __shared__ int lds[SCAN_T];
  const int tid = threadIdx.x;
  const int i = blockIdx.x * SCAN_T + tid;
  int c = (i < N) ? cnt[i] : 0;
  lds[tid] = c;
  __syncthreads();
  for (int off = 1; off < SCAN_T; off <<= 1) {
    int v = (tid >= off) ? lds[tid - off] : 0;
    __syncthreads();
    lds[tid] += v;
    __syncthreads();
  }
  if (i < N) row_ptr[i] = lds[tid] - c;
  if (tid == SCAN_T - 1) bsum[blockIdx.x] = lds[tid];
}

__global__ void k_scan2(const int* __restrict__ bsum, int* __restrict__ boffs,
                        int* __restrict__ row_ptr, int nb, int N) {
  __shared__ int lds[SCAN_T];
  const int tid = threadIdx.x;
  int v = (tid < nb) ? bsum[tid] : 0;
  lds[tid] = v;
  __syncthreads();
  for (int off = 1; off < SCAN_T; off <<= 1) {
    int t = (tid >= off) ? lds[tid - off] : 0;
    __syncthreads();
    lds[tid] += t;
    __syncthreads();
  }
  if (tid < nb) boffs[tid] = lds[tid] - v;
  if (tid == 0) row_ptr[N] = lds[nb - 1];
}

__global__ void k_scan3(int* __restrict__ row_ptr, const int* __restrict__ boffs, int N) {
  int i = blockIdx.x * SCAN_T + threadIdx.x;
  if (i < N) row_ptr[i] += boffs[blockIdx.x];
}

// per edge pair: rn = {rev CSR pos, neighbor} (8B) + initial T (16B) scattered
// into CSR order.
__global__ void k_build(const int* __restrict__ src, const int* __restrict__ dst,
                        const int* __restrict__ pos, const int* __restrict__ row_ptr,
                        const float* __restrict__ msg_init,
                        const float* __restrict__ beta,
                        int2* __restrict__ rn, __half* __restrict__ t0, int m) {
  int i = blockIdx.x * TPB + threadIdx.x;
  if (i >= m) return;
  const float b  = beta[0];
  const float ew = expf(b) - 1.0f;
  const int u = src[i], v = dst[i];
  const int pu = pos[i] + row_ptr[v];       // edge i   (u -> v): in v's segment
  const int pv = pos[i + m] + row_ptr[u];   // edge i+m (v -> u): in u's segment
  rn[pu] = make_int2(pv, u);
  rn[pv] = make_int2(pu, v);

  float r0[Q], r1[Q];
  load8(msg_init + (size_t)i * Q, r0);
  load8(msg_init + ((size_t)i + (size_t)m) * Q, r1);
  float s0 = 0.f, s1 = 0.f;
#pragma unroll
  for (int j=0;j<Q;j++) { s0 += r0[j]; s1 += r1[j]; }
  float i0 = ew / s0, i1 = ew / s1;
#pragma unroll
  for (int j=0;j<Q;j++) { r0[j] = fmaf(r0[j], i0, 1.0f); r1[j] = fmaf(r1[j], i1, 1.0f); }
  store8h(t0 + (size_t)pu * Q, r0);
  store8h(t0 + (size_t)pv * Q, r1);
}

// ---------- init ----------

// 16-thread group per node: pi0 = prod of T0 over segment (contiguous reads)
__global__ void k_pi0(const int* __restrict__ row_ptr, const __half* __restrict__ t0,
                      float* __restrict__ pi0, int N) {
  const int tid = threadIdx.x;
  const int s = tid & 15;
  const int u = (blockIdx.x * TPB + tid) >> 4;
  if (u >= N) return;
  const int st = row_ptr[u], en = row_ptr[u + 1];
  float prod[Q];
#pragma unroll
  for (int j=0;j<Q;j++) prod[j] = 1.f;
  for (int r = st + s; r < en; r += 16) {
    H8 t = *reinterpret_cast<const H8*>(t0 + (size_t)r * Q);
#pragma unroll
    for (int j=0;j<Q;j++) prod[j] *= __half2float(t.h[j]);
  }
#pragma unroll
  for (int j=0;j<Q;j++) {
    prod[j] *= __shfl_xor(prod[j], 1);
    prod[j] *= __shfl_xor(prod[j], 2);
    prod[j] *= __shfl_xor(prod[j], 4);
    prod[j] *= __shfl_xor(prod[j], 8);
  }
  if (s == 0) {
    float4* o = reinterpret_cast<float4*>(pi0 + (size_t)u * Q);
    o[0] = make_float4(prod[0], prod[1], prod[2], prod[3]);
    o[1] = make_float4(prod[4], prod[5], prod[6], prod[7]);
  }
}

__global__ void k_init_nodes(const float* __restrict__ psi_init,
                             float* __restrict__ S0, int N) {
  __shared__ float lds[WPB];
  int n = blockIdx.x * TPB + threadIdx.x;
  float p[Q];
  if (n < N) {
    load8(psi_init + (size_t)n * Q, p);
    float s = 0.f;
#pragma unroll
    for (int j=0;j<Q;j++) s += p[j];
    float inv = 1.0f / s;
#pragma unroll
    for (int j=0;j<Q;j++) p[j] *= inv;
  } else {
#pragma unroll
    for (int j=0;j<Q;j++) p[j] = 0.f;
  }
#pragma unroll
  for (int j=0;j<Q;j++) {
    block_reduce_atomic(p[j], &S0[j], lds);
  }
}

// ---------- per-iteration kernel (deferred-norm, 16 threads/node) ----------
// Thread = row-slot (stride 16), full 8-component row in regs.
// Row r in seg(u) (edge v->u), rn[r] = {rev, v}:
//   num[j] = eh[j] * pi_t[v][j] / T_t[rev][j]      (pi gather is L2-resident)
//   msg    = num / sum_j num                        (in-thread normalize)
//   T_{t+1}[r][j] = 1 + ew*msg[j]                   (contiguous fp16 write)
//   pi_{t+1}[u] = prod of T_{t+1} over segment      (16-lane shuffle product)
//   psi_{t+1}[u] = norm(pi_t[u]*eh) -> S_nxt        (threads s<8, block-reduced)
__global__ void k_iter4(const int* __restrict__ row_ptr,
                        const int2* __restrict__ rn,
                        const __half* __restrict__ tIn,
                        __half* __restrict__ tOut,
                        const float* __restrict__ pi_cur,
                        float* __restrict__ pi_nxt,
                        const float* __restrict__ beta,
                        const float* __restrict__ S,
                        float* __restrict__ S_nxt,
                        float neg_mw, int N, int writeT) {
  __shared__ float part[WPB][Q];
  const int tid = threadIdx.x;
  const int s = tid & 15;
  const float b  = beta[0];
  const float ew = expf(b) - 1.0f;
  const float hb = neg_mw * b;
  float eh[Q];
#pragma unroll
  for (int j=0;j<Q;j++) eh[j] = expf(hb * S[j]);
  const float ehs = expf(hb * S[s & 7]);
  float sacc = 0.f;

  const int u = (blockIdx.x * TPB + tid) >> 4;
  if (u < N) {
    const int st = row_ptr[u], en = row_ptr[u + 1];
    float prod[Q];
#pragma unroll
    for (int j=0;j<Q;j++) prod[j] = 1.f;

    // 2-deep pipelined gather: T[rev] scattered 16B + pi[v] 32B (L2-resident)
    int r = st + s;
    H8 c; float4 pa, pb;
    if (r < en) {
      const int2 w = rn[r];
      c  = *reinterpret_cast<const H8*>(tIn + (size_t)w.x * Q);
      const float4* pp = reinterpret_cast<const float4*>(pi_cur + (size_t)w.y * Q);
      pa = pp[0]; pb = pp[1];
    }
    while (r < en) {
      const int r2 = r + 16;
      H8 c2; float4 pa2, pb2;
      if (r2 < en) {
        const int2 w2 = rn[r2];
        c2 = *reinterpret_cast<const H8*>(tIn + (size_t)w2.x * Q);
        const float4* pp2 = reinterpret_cast<const float4*>(pi_cur + (size_t)w2.y * Q);
        pa2 = pp2[0]; pb2 = pp2[1];
      }
      float pv[Q];
      pv[0]=pa.x; pv[1]=pa.y; pv[2]=pa.z; pv[3]=pa.w;
      pv[4]=pb.x; pv[5]=pb.y; pv[6]=pb.z; pv[7]=pb.w;
      float num[Q]; float sm = 0.f;
#pragma unroll
      for (int j=0;j<Q;j++) {
        num[j] = eh[j] * pv[j] * fast_rcp(__half2float(c.h[j]));
        sm += num[j];
      }
      const float inv = fast_rcp(sm) * ew;
      H8 o;
#pragma unroll
      for (int j=0;j<Q;j++) {
        float tn = fmaf(num[j], inv, 1.0f);
        prod[j] *= tn;
        o.h[j] = __float2half(tn);
      }
      if (writeT) *reinterpret_cast<H8*>(tOut + (size_t)r * Q) = o;
      r = r2; c = c2; pa = pa2; pb = pb2;
    }
    // pi_{t+1}[u]: elementwise product across the 16 slot threads
#pragma unroll
    for (int j=0;j<Q;j++) {
      prod[j] *= __shfl_xor(prod[j], 1);
      prod[j] *= __shfl_xor(prod[j], 2);
      prod[j] *= __shfl_xor(prod[j], 4);
      prod[j] *= __shfl_xor(prod[j], 8);
    }
    if (s == 0) {
      float4* o = reinterpret_cast<float4*>(pi_nxt + (size_t)u * Q);
      o[0] = make_float4(prod[0], prod[1], prod[2], prod[3]);
      o[1] = make_float4(prod[4], prod[5], prod[6], prod[7]);
    }
    // psi_{t+1}[u][s] contribution (threads s<8 own component s; s>=8 give 0)
    if (s < Q) {
      float pn = pi_cur[(size_t)u * Q + s] * ehs;
      float smp = sum8_lanes(pn);
      sacc = pn * fast_rcp(smp);
    }
  }
  // S_nxt reduction: fold lanes with equal (lane&7)
  sacc += __shfl_xor(sacc, 8);
  sacc += __shfl_xor(sacc, 16);
  sacc += __shfl_xor(sacc, 32);
  const int lane = tid & 63, wid = tid >> 6;
  if (lane < Q) part[wid][lane] = sacc;
  __syncthreads();
  if (tid < Q) {
    float tot = 0.f;
#pragma unroll
    for (int w = 0; w < WPB; w++) tot += part[w][tid];
    atomicAdd(&S_nxt[tid], tot);
  }
}

// ---------- finalization ----------

__global__ void k_psi_ent(const float* __restrict__ pi,
                          const float* __restrict__ beta,
                          const float* __restrict__ S,
                          float neg_mw, float* __restrict__ psi,
                          float* __restrict__ H_acc, int N) {
  __shared__ float lds[WPB];
  const int j = threadIdx.x & 7;
  const float eh = expf(neg_mw * beta[0] * S[j]);
  float hacc = 0.f;
  const int g0 = (blockIdx.x * TPB + threadIdx.x) >> 3;
  const int gs = (gridDim.x * TPB) >> 3;
  for (int n = g0; n < N; n += gs) {
    float pn = pi[(size_t)n * Q + j] * eh;
    float p = pn / sum8_lanes(pn);
    psi[(size_t)n * Q + j] = p;
    float el = p * logf(p + 1e-12f);
    el = sum8_lanes(el);
    if (j == 0) hacc += el;
  }
  block_reduce_atomic(hacc, H_acc, lds);
}

__global__ void k_edge_stats(const float* __restrict__ psi,
                             const int* __restrict__ src,
                             const int* __restrict__ dst,
                             float* __restrict__ reg_acc,
                             float* __restrict__ mod_acc,
                             float one_minus_mw, int m) {
  __shared__ float lds1[WPB];
  __shared__ float lds2[WPB];
  float reg = 0.f, mod = 0.f;
  for (int i = blockIdx.x * TPB + threadIdx.x; i < m; i += gridDim.x * TPB) {
    int u = src[i], v = dst[i];
    float pu[Q], pv[Q];
    load8(psi + (size_t)u * Q, pu);
    load8(psi + (size_t)v * Q, pv);
#pragma unroll
    for (int j=0;j<Q;j++) { float d = pu[j] - pv[j]; reg += d * d; }
    int au = 0, av = 0;
    float mu = pu[0], mv = pv[0];
#pragma unroll
    for (int j=1;j<Q;j++) {
      if (pu[j] > mu) { mu = pu[j]; au = j; }
      if (pv[j] > mv) { mv = pv[j]; av = j; }
    }
    if (au == av) mod += one_minus_mw;
  }
  block_reduce_atomic(reg, reg_acc, lds1);
  block_reduce_atomic(mod, mod_acc, lds2);
}

__global__ void k_finalize(const float* __restrict__ H_acc,
                           const float* __restrict__ reg_acc,
                           const float* __restrict__ mod_acc,
                           float* __restrict__ out3,
                           float inv_m, float inv_N, float entc) {
  out3[0] = reg_acc[0] * inv_m;
  out3[1] = (-H_acc[0] * inv_N) * entc;
  out3[2] = mod_acc[0] * inv_m;
}

// ---------- host ----------

extern "C" void kernel_launch(void* const* d_in, const int* in_sizes, int n_in,
                              void* d_out, int out_size, void* d_ws, size_t ws_size,
                              hipStream_t stream) {
  const float* msg_init = (const float*)d_in[0];
  const float* psi_init = (const float*)d_in[1];
  const float* beta     = (const float*)d_in[2];
  const int*   src      = (const int*)d_in[3];
  const int*   dst      = (const int*)d_in[4];

  const int E = in_sizes[3];
  const int m = E / 2;
  const int N = in_sizes[1] / Q;
  const double mean_w = (double)E / ((double)N * (double)N);
  const float  neg_mw = (float)(-mean_w);

  float* out = (float*)d_out;

  // ---- workspace layout ----
  __half* tA = (__half*)d_ws;                       // E*Q halves
  __half* tB = tA + (size_t)E * Q;                  // E*Q halves
  int2*  rn      = (int2*)(tB + (size_t)E * Q);     // E int2
  int*   pos     = (int*)(rn + E);                  // E
  int*   row_ptr = pos + E;                         // N+1
  int*   cnt     = row_ptr + (N + 1);               // N
  int*   bsum    = cnt + N;                         // SCAN_T
  int*   boffs   = bsum + SCAN_T;                   // SCAN_T
  float* pi0     = (float*)(boffs + SCAN_T);        // N*Q
  float* pi1     = pi0 + (size_t)N * Q;             // N*Q
  float* S       = pi1 + (size_t)N * Q;             // 11*Q
  float* H_acc   = S + 11 * Q;
  float* reg_acc = H_acc + 1;
  float* mod_acc = H_acc + 2;

  const int gridC = (E + TPB * 4 - 1) / (TPB * 4);
  const int gridM = (m + TPB - 1) / TPB;
  const int gridN = (N + TPB - 1) / TPB;
  const int gridG = ((size_t)N * 16 + TPB - 1) / TPB;  // 16-thread group per node
  const int gridS = min(512, gridM);
  const int nb    = (N + SCAN_T - 1) / SCAN_T;

  const float entc  = (float)(4.0 * log(0.5) / log(1.0 / (double)Q));
  const float inv_m = (float)(1.0 / (double)m);
  const float inv_N = (float)(1.0 / (double)N);
  const float omw   = (float)(1.0 - mean_w);

  hipMemsetAsync(cnt, 0, (size_t)N * sizeof(int), stream);
  hipMemsetAsync(S, 0, (size_t)(11 * Q + 3) * sizeof(float), stream);

  // CSR build
  k_count_pos<<<gridC, TPB, 0, stream>>>(dst, cnt, pos, E);
  k_scan1<<<nb, SCAN_T, 0, stream>>>(cnt, row_ptr, bsum, N);
  k_scan2<<<1, SCAN_T, 0, stream>>>(bsum, boffs, row_ptr, nb, N);
  k_scan3<<<nb, SCAN_T, 0, stream>>>(row_ptr, boffs, N);
  k_build<<<gridM, TPB, 0, stream>>>(src, dst, pos, row_ptr, msg_init, beta,
                                     rn, tA, m);
  k_pi0<<<gridG, TPB, 0, stream>>>(row_ptr, tA, pi0, N);
  k_init_nodes<<<gridN, TPB, 0, stream>>>(psi_init, S, N);

  // 9 deferred-normalization iterations
  __half* tcur = tA; __half* tnxt = tB;
  float*  pcur = pi0; float* pnxt = pi1;
  for (int t = 0; t < 9; ++t) {
    k_iter4<<<gridG, TPB, 0, stream>>>(row_ptr, rn, tcur, tnxt, pcur, pnxt,
                                       beta, S + t * Q, S + (t + 1) * Q,
                                       neg_mw, N, (t < 8) ? 1 : 0);
    __half* th = tcur; tcur = tnxt; tnxt = th;
    float*  pf = pcur; pcur = pnxt; pnxt = pf;
  }

  // psi_10 = normalize(pi_9 * e^{h_9}), entropy fused
  k_psi_ent<<<gridN, TPB, 0, stream>>>(pcur, beta, S + 9 * Q, neg_mw, out, H_acc, N);
  k_edge_stats<<<gridS, TPB, 0, stream>>>(out, src, dst, reg_acc, mod_acc, omw, m);
  k_finalize<<<1, 1, 0, stream>>>(H_acc, reg_acc, mod_acc, out + (size_t)N * Q,
                                  inv_m, inv_N, entc);
}

// Round 12
// 757.238 us; speedup vs baseline: 2.2364x; 2.2364x over previous
//
#include <hip/hip_runtime.h>
#include <hip/hip_fp16.h>
#include <math.h>

#define Q 8
#define TPB 256
#define WPB (TPB / 64)     // waves per block
#define SCAN_T 1024

struct alignas(16) H8 { __half h[8]; };

// ---------- helpers ----------

__device__ __forceinline__ float fast_rcp(float x) {
  return __builtin_amdgcn_rcpf(x);
}

__device__ __forceinline__ void load8(const float* __restrict__ p, float r[Q]) {
  const float4* p4 = reinterpret_cast<const float4*>(p);
  float4 a = p4[0], b = p4[1];
  r[0]=a.x; r[1]=a.y; r[2]=a.z; r[3]=a.w;
  r[4]=b.x; r[5]=b.y; r[6]=b.z; r[7]=b.w;
}

__device__ __forceinline__ void store8h(__half* __restrict__ p, const float r[Q]) {
  H8 t;
#pragma unroll
  for (int j=0;j<Q;j++) t.h[j] = __float2half(r[j]);
  *reinterpret_cast<H8*>(p) = t;
}

__device__ __forceinline__ float wave_sum(float x) {
  x += __shfl_down(x, 32);
  x += __shfl_down(x, 16);
  x += __shfl_down(x, 8);
  x += __shfl_down(x, 4);
  x += __shfl_down(x, 2);
  x += __shfl_down(x, 1);
  return x;
}

__device__ __forceinline__ void block_reduce_atomic(float x, float* target, float* lds) {
  float w = wave_sum(x);
  const int lane = threadIdx.x & 63, wid = threadIdx.x >> 6;
  if (lane == 0) lds[wid] = w;
  __syncthreads();
  if (threadIdx.x == 0) {
    float t = 0.f;
#pragma unroll
    for (int i = 0; i < WPB; i++) t += lds[i];
    atomicAdd(target, t);
  }
  __syncthreads();
}

__device__ __forceinline__ float sum8_lanes(float x) {
  x += __shfl_xor(x, 1);
  x += __shfl_xor(x, 2);
  x += __shfl_xor(x, 4);
  return x;
}

// ---------- CSR build ----------

// plain count, NO-return atomics (fire-and-forget)
__global__ void k_count(const int* __restrict__ dst, int* __restrict__ cnt, int E) {
  int i0 = (blockIdx.x * TPB + threadIdx.x) * 4;
  if (i0 + 3 < E) {
    int4 d = *reinterpret_cast<const int4*>(dst + i0);
    atomicAdd(&cnt[d.x], 1);
    atomicAdd(&cnt[d.y], 1);
    atomicAdd(&cnt[d.z], 1);
    atomicAdd(&cnt[d.w], 1);
  } else {
    for (int e = i0; e < E; e++) atomicAdd(&cnt[dst[e]], 1);
  }
}

__global__ void k_scan1(const int* __restrict__ cnt, int* __restrict__ row_ptr,
                        int* __restrict__ bsum, int N) {
  __shared__ int lds[SCAN_T];
  const int tid = threadIdx.x;
  const int i = blockIdx.x * SCAN_T + tid;
  int c = (i < N) ? cnt[i] : 0;
  lds[tid] = c;
  __syncthreads();
  for (int off = 1; off < SCAN_T; off <<= 1) {
    int v = (tid >= off) ? lds[tid - off] : 0;
    __syncthreads();
    lds[tid] += v;
    __syncthreads();
  }
  if (i < N) row_ptr[i] = lds[tid] - c;
  if (tid == SCAN_T - 1) bsum[blockIdx.x] = lds[tid];
}

__global__ void k_scan2(const int* __restrict__ bsum, int* __restrict__ boffs,
                        int* __restrict__ row_ptr, int nb, int N) {
  __shared__ int lds[SCAN_T];
  const int tid = threadIdx.x;
  int v = (tid < nb) ? bsum[tid] : 0;
  lds[tid] = v;
  __syncthreads();
  for (int off = 1; off < SCAN_T; off <<= 1) {
    int t = (tid >= off) ? lds[tid - off] : 0;
    __syncthreads();
    lds[tid] += t;
    __syncthreads();
  }
  if (tid < nb) boffs[tid] = lds[tid] - v;
  if (tid == 0) row_ptr[N] = lds[nb - 1];
}

// finalize row_ptr AND produce the cursor copy for k_build's rank atomics
__global__ void k_scan3(int* __restrict__ row_ptr, int* __restrict__ cursor,
                        const int* __restrict__ boffs, int N) {
  int i = blockIdx.x * SCAN_T + threadIdx.x;
  if (i < N) {
    int r = row_ptr[i] + boffs[blockIdx.x];
    row_ptr[i] = r;
    cursor[i] = r;
  }
}

// per edge pair: rank atomics fused in; rn = {rev CSR pos, neighbor} (8B) +
// initial T (16B) scattered into CSR order.
__global__ void k_build(const int* __restrict__ src, const int* __restrict__ dst,
                        int* __restrict__ cursor,
                        const float* __restrict__ msg_init,
                        const float* __restrict__ beta,
                        int2* __restrict__ rn, __half* __restrict__ t0, int m) {
  int i = blockIdx.x * TPB + threadIdx.x;
  if (i >= m) return;
  const float b  = beta[0];
  const float ew = expf(b) - 1.0f;
  const int u = src[i], v = dst[i];
  const int pu = atomicAdd(&cursor[v], 1);   // edge i   (u -> v): slot in v's segment
  const int pv = atomicAdd(&cursor[u], 1);   // edge i+m (v -> u): slot in u's segment
  rn[pu] = make_int2(pv, u);
  rn[pv] = make_int2(pu, v);

  float r0[Q], r1[Q];
  load8(msg_init + (size_t)i * Q, r0);
  load8(msg_init + ((size_t)i + (size_t)m) * Q, r1);
  float s0 = 0.f, s1 = 0.f;
#pragma unroll
  for (int j=0;j<Q;j++) { s0 += r0[j]; s1 += r1[j]; }
  float i0 = ew / s0, i1 = ew / s1;
#pragma unroll
  for (int j=0;j<Q;j++) { r0[j] = fmaf(r0[j], i0, 1.0f); r1[j] = fmaf(r1[j], i1, 1.0f); }
  store8h(t0 + (size_t)pu * Q, r0);
  store8h(t0 + (size_t)pv * Q, r1);
}

// ---------- init ----------

// 8-thread group per node: pi0 = prod of T0 over segment (contiguous reads)
__global__ void k_pi0(const int* __restrict__ row_ptr, const __half* __restrict__ t0,
                      float* __restrict__ pi0, int N) {
  const int tid = threadIdx.x;
  const int s = tid & 7;
  const int u = (blockIdx.x * TPB + tid) >> 3;
  if (u >= N) return;
  const int st = row_ptr[u], en = row_ptr[u + 1];
  float prod[Q];
#pragma unroll
  for (int j=0;j<Q;j++) prod[j] = 1.f;
  for (int r = st + s; r < en; r += 8) {
    H8 t = *reinterpret_cast<const H8*>(t0 + (size_t)r * Q);
#pragma unroll
    for (int j=0;j<Q;j++) prod[j] *= __half2float(t.h[j]);
  }
#pragma unroll
  for (int j=0;j<Q;j++) {
    prod[j] *= __shfl_xor(prod[j], 1);
    prod[j] *= __shfl_xor(prod[j], 2);
    prod[j] *= __shfl_xor(prod[j], 4);
  }
  if (s == 0) {
    float4* o = reinterpret_cast<float4*>(pi0 + (size_t)u * Q);
    o[0] = make_float4(prod[0], prod[1], prod[2], prod[3]);
    o[1] = make_float4(prod[4], prod[5], prod[6], prod[7]);
  }
}

__global__ void k_init_nodes(const float* __restrict__ psi_init,
                             float* __restrict__ S0, int N) {
  __shared__ float lds[WPB];
  int n = blockIdx.x * TPB + threadIdx.x;
  float p[Q];
  if (n < N) {
    load8(psi_init + (size_t)n * Q, p);
    float s = 0.f;
#pragma unroll
    for (int j=0;j<Q;j++) s += p[j];
    float inv = 1.0f / s;
#pragma unroll
    for (int j=0;j<Q;j++) p[j] *= inv;
  } else {
#pragma unroll
    for (int j=0;j<Q;j++) p[j] = 0.f;
  }
#pragma unroll
  for (int j=0;j<Q;j++) {
    block_reduce_atomic(p[j], &S0[j], lds);
  }
}

// ---------- per-iteration kernel (deferred-norm, 8 threads/node — round-10 best) ----------
__global__ void k_iter3(const int* __restrict__ row_ptr,
                        const int2* __restrict__ rn,
                        const __half* __restrict__ tIn,
                        __half* __restrict__ tOut,
                        const float* __restrict__ pi_cur,
                        float* __restrict__ pi_nxt,
                        const float* __restrict__ beta,
                        const float* __restrict__ S,
                        float* __restrict__ S_nxt,
                        float neg_mw, int N, int writeT) {
  __shared__ float part[WPB][Q];
  const int tid = threadIdx.x;
  const int s = tid & 7;
  const float b  = beta[0];
  const float ew = expf(b) - 1.0f;
  const float hb = neg_mw * b;
  float eh[Q];
#pragma unroll
  for (int j=0;j<Q;j++) eh[j] = expf(hb * S[j]);
  const float ehs = expf(hb * S[s]);
  float sacc = 0.f;

  const int u = (blockIdx.x * TPB + tid) >> 3;
  if (u < N) {
    const int st = row_ptr[u], en = row_ptr[u + 1];
    float prod[Q];
#pragma unroll
    for (int j=0;j<Q;j++) prod[j] = 1.f;

    // 2-deep pipelined gather: T[rev] scattered 16B + pi[v] 32B (L2-resident)
    int r = st + s;
    H8 c; float4 pa, pb;
    if (r < en) {
      const int2 w = rn[r];
      c  = *reinterpret_cast<const H8*>(tIn + (size_t)w.x * Q);
      const float4* pp = reinterpret_cast<const float4*>(pi_cur + (size_t)w.y * Q);
      pa = pp[0]; pb = pp[1];
    }
    while (r < en) {
      const int r2 = r + 8;
      H8 c2; float4 pa2, pb2;
      if (r2 < en) {
        const int2 w2 = rn[r2];
        c2 = *reinterpret_cast<const H8*>(tIn + (size_t)w2.x * Q);
        const float4* pp2 = reinterpret_cast<const float4*>(pi_cur + (size_t)w2.y * Q);
        pa2 = pp2[0]; pb2 = pp2[1];
      }
      float pv[Q];
      pv[0]=pa.x; pv[1]=pa.y; pv[2]=pa.z; pv[3]=pa.w;
      pv[4]=pb.x; pv[5]=pb.y; pv[6]=pb.z; pv[7]=pb.w;
      float num[Q]; float sm = 0.f;
#pragma unroll
      for (int j=0;j<Q;j++) {
        num[j] = eh[j] * pv[j] * fast_rcp(__half2float(c.h[j]));
        sm += num[j];
      }
      const float inv = fast_rcp(sm) * ew;
      H8 o;
#pragma unroll
      for (int j=0;j<Q;j++) {
        float tn = fmaf(num[j], inv, 1.0f);
        prod[j] *= tn;
        o.h[j] = __float2half(tn);
      }
      if (writeT) *reinterpret_cast<H8*>(tOut + (size_t)r * Q) = o;
      r = r2; c = c2; pa = pa2; pb = pb2;
    }
    // pi_{t+1}[u]: elementwise product across the 8 slot threads
#pragma unroll
    for (int j=0;j<Q;j++) {
      prod[j] *= __shfl_xor(prod[j], 1);
      prod[j] *= __shfl_xor(prod[j], 2);
      prod[j] *= __shfl_xor(prod[j], 4);
    }
    if (s == 0) {
      float4* o = reinterpret_cast<float4*>(pi_nxt + (size_t)u * Q);
      o[0] = make_float4(prod[0], prod[1], prod[2], prod[3]);
      o[1] = make_float4(prod[4], prod[5], prod[6], prod[7]);
    }
    // psi_{t+1}[u][s] contribution (thread s owns component s)
    {
      float pn = pi_cur[(size_t)u * Q + s] * ehs;
      float smp = sum8_lanes(pn);
      sacc = pn * fast_rcp(smp);
    }
  }
  // S_nxt reduction
  sacc += __shfl_xor(sacc, 8);
  sacc += __shfl_xor(sacc, 16);
  sacc += __shfl_xor(sacc, 32);
  const int lane = tid & 63, wid = tid >> 6;
  if (lane < Q) part[wid][lane] = sacc;
  __syncthreads();
  if (tid < Q) {
    float tot = 0.f;
#pragma unroll
    for (int w = 0; w < WPB; w++) tot += part[w][tid];
    atomicAdd(&S_nxt[tid], tot);
  }
}

// ---------- finalization ----------

__global__ void k_psi_ent(const float* __restrict__ pi,
                          const float* __restrict__ beta,
                          const float* __restrict__ S,
                          float neg_mw, float* __restrict__ psi,
                          float* __restrict__ H_acc, int N) {
  __shared__ float lds[WPB];
  const int j = threadIdx.x & 7;
  const float eh = expf(neg_mw * beta[0] * S[j]);
  float hacc = 0.f;
  const int g0 = (blockIdx.x * TPB + threadIdx.x) >> 3;
  const int gs = (gridDim.x * TPB) >> 3;
  for (int n = g0; n < N; n += gs) {
    float pn = pi[(size_t)n * Q + j] * eh;
    float p = pn / sum8_lanes(pn);
    psi[(size_t)n * Q + j] = p;
    float el = p * logf(p + 1e-12f);
    el = sum8_lanes(el);
    if (j == 0) hacc += el;
  }
  block_reduce_atomic(hacc, H_acc, lds);
}

__global__ void k_edge_stats(const float* __restrict__ psi,
                             const int* __restrict__ src,
                             const int* __restrict__ dst,
                             float* __restrict__ reg_acc,
                             float* __restrict__ mod_acc,
                             float one_minus_mw, int m) {
  __shared__ float lds1[WPB];
  __shared__ float lds2[WPB];
  float reg = 0.f, mod = 0.f;
  for (int i = blockIdx.x * TPB + threadIdx.x; i < m; i += gridDim.x * TPB) {
    int u = src[i], v = dst[i];
    float pu[Q], pv[Q];
    load8(psi + (size_t)u * Q, pu);
    load8(psi + (size_t)v * Q, pv);
#pragma unroll
    for (int j=0;j<Q;j++) { float d = pu[j] - pv[j]; reg += d * d; }
    int au = 0, av = 0;
    float mu = pu[0], mv = pv[0];
#pragma unroll
    for (int j=1;j<Q;j++) {
      if (pu[j] > mu) { mu = pu[j]; au = j; }
      if (pv[j] > mv) { mv = pv[j]; av = j; }
    }
    if (au == av) mod += one_minus_mw;
  }
  block_reduce_atomic(reg, reg_acc, lds1);
  block_reduce_atomic(mod, mod_acc, lds2);
}

__global__ void k_finalize(const float* __restrict__ H_acc,
                           const float* __restrict__ reg_acc,
                           const float* __restrict__ mod_acc,
                           float* __restrict__ out3,
                           float inv_m, float inv_N, float entc) {
  out3[0] = reg_acc[0] * inv_m;
  out3[1] = (-H_acc[0] * inv_N) * entc;
  out3[2] = mod_acc[0] * inv_m;
}

// ---------- host ----------

extern "C" void kernel_launch(void* const* d_in, const int* in_sizes, int n_in,
                              void* d_out, int out_size, void* d_ws, size_t ws_size,
                              hipStream_t stream) {
  const float* msg_init = (const float*)d_in[0];
  const float* psi_init = (const float*)d_in[1];
  const float* beta     = (const float*)d_in[2];
  const int*   src      = (const int*)d_in[3];
  const int*   dst      = (const int*)d_in[4];

  const int E = in_sizes[3];
  const int m = E / 2;
  const int N = in_sizes[1] / Q;
  const double mean_w = (double)E / ((double)N * (double)N);
  const float  neg_mw = (float)(-mean_w);

  float* out = (float*)d_out;

  // ---- workspace layout ----
  __half* tA = (__half*)d_ws;                       // E*Q halves
  __half* tB = tA + (size_t)E * Q;                  // E*Q halves
  int2*  rn      = (int2*)(tB + (size_t)E * Q);     // E int2
  int*   row_ptr = (int*)(rn + E);                  // N+1
  int*   cnt     = row_ptr + (N + 1);               // N
  int*   cursor  = cnt + N;                         // N
  int*   bsum    = cursor + N;                      // SCAN_T
  int*   boffs   = bsum + SCAN_T;                   // SCAN_T
  float* pi0     = (float*)(boffs + SCAN_T);        // N*Q
  float* pi1     = pi0 + (size_t)N * Q;             // N*Q
  float* S       = pi1 + (size_t)N * Q;             // 11*Q
  float* H_acc   = S + 11 * Q;
  float* reg_acc = H_acc + 1;
  float* mod_acc = H_acc + 2;

  const int gridC = (E + TPB * 4 - 1) / (TPB * 4);
  const int gridM = (m + TPB - 1) / TPB;
  const int gridN = (N + TPB - 1) / TPB;
  const int gridG = ((size_t)N * Q + TPB - 1) / TPB;   // 8-thread group per node
  const int gridS = min(512, gridM);
  const int nb    = (N + SCAN_T - 1) / SCAN_T;

  const float entc  = (float)(4.0 * log(0.5) / log(1.0 / (double)Q));
  const float inv_m = (float)(1.0 / (double)m);
  const float inv_N = (float)(1.0 / (double)N);
  const float omw   = (float)(1.0 - mean_w);

  hipMemsetAsync(cnt, 0, (size_t)N * sizeof(int), stream);
  hipMemsetAsync(S, 0, (size_t)(11 * Q + 3) * sizeof(float), stream);

  // CSR build: no-return count -> scan -> build (rank atomics fused)
  k_count<<<gridC, TPB, 0, stream>>>(dst, cnt, E);
  k_scan1<<<nb, SCAN_T, 0, stream>>>(cnt, row_ptr, bsum, N);
  k_scan2<<<1, SCAN_T, 0, stream>>>(bsum, boffs, row_ptr, nb, N);
  k_scan3<<<nb, SCAN_T, 0, stream>>>(row_ptr, cursor, boffs, N);
  k_build<<<gridM, TPB, 0, stream>>>(src, dst, cursor, msg_init, beta, rn, tA, m);
  k_pi0<<<gridG, TPB, 0, stream>>>(row_ptr, tA, pi0, N);
  k_init_nodes<<<gridN, TPB, 0, stream>>>(psi_init, S, N);

  // 9 deferred-normalization iterations
  __half* tcur = tA; __half* tnxt = tB;
  float*  pcur = pi0; float* pnxt = pi1;
  for (int t = 0; t < 9; ++t) {
    k_iter3<<<gridG, TPB, 0, stream>>>(row_ptr, rn, tcur, tnxt, pcur, pnxt,
                                       beta, S + t * Q, S + (t + 1) * Q,
                                       neg_mw, N, (t < 8) ? 1 : 0);
    __half* th = tcur; tcur = tnxt; tnxt = th;
    float*  pf = pcur; pcur = pnxt; pnxt = pf;
  }

  // psi_10 = normalize(pi_9 * e^{h_9}), entropy fused
  k_psi_ent<<<gridN, TPB, 0, stream>>>(pcur, beta, S + 9 * Q, neg_mw, out, H_acc, N);
  k_edge_stats<<<gridS, TPB, 0, stream>>>(out, src, dst, reg_acc, mod_acc, omw, m);
  k_finalize<<<1, 1, 0, stream>>>(H_acc, reg_acc, mod_acc, out + (size_t)N * Q,
                                  inv_m, inv_N, entc);
}

// Round 13
// 675.219 us; speedup vs baseline: 2.5081x; 1.1215x over previous
//
#include <hip/hip_runtime.h>
#include <hip/hip_fp16.h>
#include <math.h>

#define Q 8
#define TPB 256
#define WPB (TPB / 64)     // waves per block
#define SCAN_T 1024

struct alignas(16) H8 { __half h[8]; };

// ---------- helpers ----------

__device__ __forceinline__ float fast_rcp(float x) {
  return __builtin_amdgcn_rcpf(x);
}

__device__ __forceinline__ void load8(const float* __restrict__ p, float r[Q]) {
  const float4* p4 = reinterpret_cast<const float4*>(p);
  float4 a = p4[0], b = p4[1];
  r[0]=a.x; r[1]=a.y; r[2]=a.z; r[3]=a.w;
  r[4]=b.x; r[5]=b.y; r[6]=b.z; r[7]=b.w;
}

__device__ __forceinline__ void store8h(__half* __restrict__ p, const float r[Q]) {
  H8 t;
#pragma unroll
  for (int j=0;j<Q;j++) t.h[j] = __float2half(r[j]);
  *reinterpret_cast<H8*>(p) = t;
}

__device__ __forceinline__ float wave_sum(float x) {
  x += __shfl_down(x, 32);
  x += __shfl_down(x, 16);
  x += __shfl_down(x, 8);
  x += __shfl_down(x, 4);
  x += __shfl_down(x, 2);
  x += __shfl_down(x, 1);
  return x;
}

__device__ __forceinline__ void block_reduce_atomic(float x, float* target, float* lds) {
  float w = wave_sum(x);
  const int lane = threadIdx.x & 63, wid = threadIdx.x >> 6;
  if (lane == 0) lds[wid] = w;
  __syncthreads();
  if (threadIdx.x == 0) {
    float t = 0.f;
#pragma unroll
    for (int i = 0; i < WPB; i++) t += lds[i];
    atomicAdd(target, t);
  }
  __syncthreads();
}

__device__ __forceinline__ float sum8_lanes(float x) {
  x += __shfl_xor(x, 1);
  x += __shfl_xor(x, 2);
  x += __shfl_xor(x, 4);
  return x;
}

// ---------- CSR build (4-way sub-counters to cut same-address contention) ----------

// count + local rank into cnt4[dst*4 + (e&3)]; 4 edges per thread
__global__ void k_count_pos(const int* __restrict__ dst, int* __restrict__ cnt4,
                            int* __restrict__ pos, int E) {
  int i0 = (blockIdx.x * TPB + threadIdx.x) * 4;
  if (i0 + 3 < E) {
    int4 d = *reinterpret_cast<const int4*>(dst + i0);
    int p0 = atomicAdd(&cnt4[d.x * 4 + ((i0    ) & 3)], 1);
    int p1 = atomicAdd(&cnt4[d.y * 4 + ((i0 + 1) & 3)], 1);
    int p2 = atomicAdd(&cnt4[d.z * 4 + ((i0 + 2) & 3)], 1);
    int p3 = atomicAdd(&cnt4[d.w * 4 + ((i0 + 3) & 3)], 1);
    *reinterpret_cast<int4*>(pos + i0) = make_int4(p0, p1, p2, p3);
  } else {
    for (int e = i0; e < E; e++) pos[e] = atomicAdd(&cnt4[dst[e] * 4 + (e & 3)], 1);
  }
}

// block-local exclusive scan over 4N sub-counters
__global__ void k_scan1(const int* __restrict__ cnt4, int* __restrict__ rp4,
                        int* __restrict__ bsum, int N4) {
  __shared__ int lds[SCAN_T];
  const int tid = threadIdx.x;
  const int i = blockIdx.x * SCAN_T + tid;
  int c = (i < N4) ? cnt4[i] : 0;
  lds[tid] = c;
  __syncthreads();
  for (int off = 1; off < SCAN_T; off <<= 1) {
    int v = (tid >= off) ? lds[tid - off] : 0;
    __syncthreads();
    lds[tid] += v;
    __syncthreads();
  }
  if (i < N4) rp4[i] = lds[tid] - c;
  if (tid == SCAN_T - 1) bsum[blockIdx.x] = lds[tid];
}

__global__ void k_scan2(const int* __restrict__ bsum, int* __restrict__ boffs,
                        int* __restrict__ row_ptr, int nb, int N) {
  __shared__ int lds[SCAN_T];
  const int tid = threadIdx.x;
  int v = (tid < nb) ? bsum[tid] : 0;
  lds[tid] = v;
  __syncthreads();
  for (int off = 1; off < SCAN_T; off <<= 1) {
    int t = (tid >= off) ? lds[tid - off] : 0;
    __syncthreads();
    lds[tid] += t;
    __syncthreads();
  }
  if (tid < nb) boffs[tid] = lds[tid] - v;
  if (tid == 0) row_ptr[N] = lds[nb - 1];
}

// finalize rp4; extract per-node row_ptr (= rp4 at sub 0)
__global__ void k_scan3(int* __restrict__ rp4, int* __restrict__ row_ptr,
                        const int* __restrict__ boffs, int N4) {
  int i = blockIdx.x * SCAN_T + threadIdx.x;
  if (i < N4) {
    int r = rp4[i] + boffs[blockIdx.x];
    rp4[i] = r;
    if ((i & 3) == 0) row_ptr[i >> 2] = r;
  }
}

// per edge pair: rn = {rev CSR pos, neighbor} (8B) + initial T (16B) scattered
// into CSR order. Global positions recombined from sub-counter rank + rp4.
__global__ void k_build(const int* __restrict__ src, const int* __restrict__ dst,
                        const int* __restrict__ pos, const int* __restrict__ rp4,
                        const float* __restrict__ msg_init,
                        const float* __restrict__ beta,
                        int2* __restrict__ rn, __half* __restrict__ t0, int m) {
  int i = blockIdx.x * TPB + threadIdx.x;
  if (i >= m) return;
  const float b  = beta[0];
  const float ew = expf(b) - 1.0f;
  const int u = src[i], v = dst[i];
  const int pu = pos[i]     + rp4[v * 4 + (i & 3)];         // edge i   (u -> v)
  const int pv = pos[i + m] + rp4[u * 4 + ((i + m) & 3)];   // edge i+m (v -> u)
  rn[pu] = make_int2(pv, u);
  rn[pv] = make_int2(pu, v);

  float r0[Q], r1[Q];
  load8(msg_init + (size_t)i * Q, r0);
  load8(msg_init + ((size_t)i + (size_t)m) * Q, r1);
  float s0 = 0.f, s1 = 0.f;
#pragma unroll
  for (int j=0;j<Q;j++) { s0 += r0[j]; s1 += r1[j]; }
  float i0 = ew / s0, i1 = ew / s1;
#pragma unroll
  for (int j=0;j<Q;j++) { r0[j] = fmaf(r0[j], i0, 1.0f); r1[j] = fmaf(r1[j], i1, 1.0f); }
  store8h(t0 + (size_t)pu * Q, r0);
  store8h(t0 + (size_t)pv * Q, r1);
}

// ---------- init ----------

// 8-thread group per node: pi0 = prod of T0 over segment (contiguous reads)
__global__ void k_pi0(const int* __restrict__ row_ptr, const __half* __restrict__ t0,
                      float* __restrict__ pi0, int N) {
  const int tid = threadIdx.x;
  const int s = tid & 7;
  const int u = (blockIdx.x * TPB + tid) >> 3;
  if (u >= N) return;
  const int st = row_ptr[u], en = row_ptr[u + 1];
  float prod[Q];
#pragma unroll
  for (int j=0;j<Q;j++) prod[j] = 1.f;
  for (int r = st + s; r < en; r += 8) {
    H8 t = *reinterpret_cast<const H8*>(t0 + (size_t)r * Q);
#pragma unroll
    for (int j=0;j<Q;j++) prod[j] *= __half2float(t.h[j]);
  }
#pragma unroll
  for (int j=0;j<Q;j++) {
    prod[j] *= __shfl_xor(prod[j], 1);
    prod[j] *= __shfl_xor(prod[j], 2);
    prod[j] *= __shfl_xor(prod[j], 4);
  }
  if (s == 0) {
    float4* o = reinterpret_cast<float4*>(pi0 + (size_t)u * Q);
    o[0] = make_float4(prod[0], prod[1], prod[2], prod[3]);
    o[1] = make_float4(prod[4], prod[5], prod[6], prod[7]);
  }
}

// single-syncthreads version: wave-reduce all 8 comps, one LDS pass
__global__ void k_init_nodes(const float* __restrict__ psi_init,
                             float* __restrict__ S0, int N) {
  __shared__ float part[WPB][Q];
  int n = blockIdx.x * TPB + threadIdx.x;
  float p[Q];
  if (n < N) {
    load8(psi_init + (size_t)n * Q, p);
    float s = 0.f;
#pragma unroll
    for (int j=0;j<Q;j++) s += p[j];
    float inv = 1.0f / s;
#pragma unroll
    for (int j=0;j<Q;j++) p[j] *= inv;
  } else {
#pragma unroll
    for (int j=0;j<Q;j++) p[j] = 0.f;
  }
  const int lane = threadIdx.x & 63, wid = threadIdx.x >> 6;
#pragma unroll
  for (int j=0;j<Q;j++) {
    float w = wave_sum(p[j]);
    if (lane == 0) part[wid][j] = w;
  }
  __syncthreads();
  if (threadIdx.x < Q) {
    float tot = 0.f;
#pragma unroll
    for (int w = 0; w < WPB; w++) tot += part[w][threadIdx.x];
    atomicAdd(&S0[threadIdx.x], tot);
  }
}

// ---------- per-iteration kernel (deferred-norm, 8 threads/node — round-10 best) ----------
__global__ void k_iter3(const int* __restrict__ row_ptr,
                        const int2* __restrict__ rn,
                        const __half* __restrict__ tIn,
                        __half* __restrict__ tOut,
                        const float* __restrict__ pi_cur,
                        float* __restrict__ pi_nxt,
                        const float* __restrict__ beta,
                        const float* __restrict__ S,
                        float* __restrict__ S_nxt,
                        float neg_mw, int N, int writeT) {
  __shared__ float part[WPB][Q];
  const int tid = threadIdx.x;
  const int s = tid & 7;
  const float b  = beta[0];
  const float ew = expf(b) - 1.0f;
  const float hb = neg_mw * b;
  float eh[Q];
#pragma unroll
  for (int j=0;j<Q;j++) eh[j] = expf(hb * S[j]);
  const float ehs = expf(hb * S[s]);
  float sacc = 0.f;

  const int u = (blockIdx.x * TPB + tid) >> 3;
  if (u < N) {
    const int st = row_ptr[u], en = row_ptr[u + 1];
    float prod[Q];
#pragma unroll
    for (int j=0;j<Q;j++) prod[j] = 1.f;

    // 2-deep pipelined gather: T[rev] scattered 16B + pi[v] 32B (L2-resident)
    int r = st + s;
    H8 c; float4 pa, pb;
    if (r < en) {
      const int2 w = rn[r];
      c  = *reinterpret_cast<const H8*>(tIn + (size_t)w.x * Q);
      const float4* pp = reinterpret_cast<const float4*>(pi_cur + (size_t)w.y * Q);
      pa = pp[0]; pb = pp[1];
    }
    while (r < en) {
      const int r2 = r + 8;
      H8 c2; float4 pa2, pb2;
      if (r2 < en) {
        const int2 w2 = rn[r2];
        c2 = *reinterpret_cast<const H8*>(tIn + (size_t)w2.x * Q);
        const float4* pp2 = reinterpret_cast<const float4*>(pi_cur + (size_t)w2.y * Q);
        pa2 = pp2[0]; pb2 = pp2[1];
      }
      float pv[Q];
      pv[0]=pa.x; pv[1]=pa.y; pv[2]=pa.z; pv[3]=pa.w;
      pv[4]=pb.x; pv[5]=pb.y; pv[6]=pb.z; pv[7]=pb.w;
      float num[Q]; float sm = 0.f;
#pragma unroll
      for (int j=0;j<Q;j++) {
        num[j] = eh[j] * pv[j] * fast_rcp(__half2float(c.h[j]));
        sm += num[j];
      }
      const float inv = fast_rcp(sm) * ew;
      H8 o;
#pragma unroll
      for (int j=0;j<Q;j++) {
        float tn = fmaf(num[j], inv, 1.0f);
        prod[j] *= tn;
        o.h[j] = __float2half(tn);
      }
      if (writeT) *reinterpret_cast<H8*>(tOut + (size_t)r * Q) = o;
      r = r2; c = c2; pa = pa2; pb = pb2;
    }
    // pi_{t+1}[u]: elementwise product across the 8 slot threads
#pragma unroll
    for (int j=0;j<Q;j++) {
      prod[j] *= __shfl_xor(prod[j], 1);
      prod[j] *= __shfl_xor(prod[j], 2);
      prod[j] *= __shfl_xor(prod[j], 4);
    }
    if (s == 0) {
      float4* o = reinterpret_cast<float4*>(pi_nxt + (size_t)u * Q);
      o[0] = make_float4(prod[0], prod[1], prod[2], prod[3]);
      o[1] = make_float4(prod[4], prod[5], prod[6], prod[7]);
    }
    // psi_{t+1}[u][s] contribution (thread s owns component s)
    {
      float pn = pi_cur[(size_t)u * Q + s] * ehs;
      float smp = sum8_lanes(pn);
      sacc = pn * fast_rcp(smp);
    }
  }
  // S_nxt reduction
  sacc += __shfl_xor(sacc, 8);
  sacc += __shfl_xor(sacc, 16);
  sacc += __shfl_xor(sacc, 32);
  const int lane = tid & 63, wid = tid >> 6;
  if (lane < Q) part[wid][lane] = sacc;
  __syncthreads();
  if (tid < Q) {
    float tot = 0.f;
#pragma unroll
    for (int w = 0; w < WPB; w++) tot += part[w][tid];
    atomicAdd(&S_nxt[tid], tot);
  }
}

// ---------- finalization ----------

__global__ void k_psi_ent(const float* __restrict__ pi,
                          const float* __restrict__ beta,
                          const float* __restrict__ S,
                          float neg_mw, float* __restrict__ psi,
                          float* __restrict__ H_acc, int N) {
  __shared__ float lds[WPB];
  const int j = threadIdx.x & 7;
  const float eh = expf(neg_mw * beta[0] * S[j]);
  float hacc = 0.f;
  const int g0 = (blockIdx.x * TPB + threadIdx.x) >> 3;
  const int gs = (gridDim.x * TPB) >> 3;
  for (int n = g0; n < N; n += gs) {
    float pn = pi[(size_t)n * Q + j] * eh;
    float p = pn / sum8_lanes(pn);
    psi[(size_t)n * Q + j] = p;
    float el = p * logf(p + 1e-12f);
    el = sum8_lanes(el);
    if (j == 0) hacc += el;
  }
  block_reduce_atomic(hacc, H_acc, lds);
}

__global__ void k_edge_stats(const float* __restrict__ psi,
                             const int* __restrict__ src,
                             const int* __restrict__ dst,
                             float* __restrict__ reg_acc,
                             float* __restrict__ mod_acc,
                             float one_minus_mw, int m) {
  __shared__ float lds1[WPB];
  __shared__ float lds2[WPB];
  float reg = 0.f, mod = 0.f;
  for (int i = blockIdx.x * TPB + threadIdx.x; i < m; i += gridDim.x * TPB) {
    int u = src[i], v = dst[i];
    float pu[Q], pv[Q];
    load8(psi + (size_t)u * Q, pu);
    load8(psi + (size_t)v * Q, pv);
#pragma unroll
    for (int j=0;j<Q;j++) { float d = pu[j] - pv[j]; reg += d * d; }
    int au = 0, av = 0;
    float mu = pu[0], mv = pv[0];
#pragma unroll
    for (int j=1;j<Q;j++) {
      if (pu[j] > mu) { mu = pu[j]; au = j; }
      if (pv[j] > mv) { mv = pv[j]; av = j; }
    }
    if (au == av) mod += one_minus_mw;
  }
  block_reduce_atomic(reg, reg_acc, lds1);
  block_reduce_atomic(mod, mod_acc, lds2);
}

__global__ void k_finalize(const float* __restrict__ H_acc,
                           const float* __restrict__ reg_acc,
                           const float* __restrict__ mod_acc,
                           float* __restrict__ out3,
                           float inv_m, float inv_N, float entc) {
  out3[0] = reg_acc[0] * inv_m;
  out3[1] = (-H_acc[0] * inv_N) * entc;
  out3[2] = mod_acc[0] * inv_m;
}

// ---------- host ----------

extern "C" void kernel_launch(void* const* d_in, const int* in_sizes, int n_in,
                              void* d_out, int out_size, void* d_ws, size_t ws_size,
                              hipStream_t stream) {
  const float* msg_init = (const float*)d_in[0];
  const float* psi_init = (const float*)d_in[1];
  const float* beta     = (const float*)d_in[2];
  const int*   src      = (const int*)d_in[3];
  const int*   dst      = (const int*)d_in[4];

  const int E = in_sizes[3];
  const int m = E / 2;
  const int N = in_sizes[1] / Q;
  const int N4 = 4 * N;
  const double mean_w = (double)E / ((double)N * (double)N);
  const float  neg_mw = (float)(-mean_w);

  float* out = (float*)d_out;

  // ---- workspace layout ----
  __half* tA = (__half*)d_ws;                       // E*Q halves
  __half* tB = tA + (size_t)E * Q;                  // E*Q halves
  int2*  rn      = (int2*)(tB + (size_t)E * Q);     // E int2
  int*   pos     = (int*)(rn + E);                  // E
  int*   rp4     = pos + E;                         // 4N
  int*   cnt4    = rp4 + N4;                        // 4N
  int*   row_ptr = cnt4 + N4;                       // N+1
  int*   bsum    = row_ptr + (N + 1);               // SCAN_T
  int*   boffs   = bsum + SCAN_T;                   // SCAN_T
  float* pi0     = (float*)(boffs + SCAN_T);        // N*Q
  float* pi1     = pi0 + (size_t)N * Q;             // N*Q
  float* S       = pi1 + (size_t)N * Q;             // 11*Q
  float* H_acc   = S + 11 * Q;
  float* reg_acc = H_acc + 1;
  float* mod_acc = H_acc + 2;

  const int gridC = (E + TPB * 4 - 1) / (TPB * 4);
  const int gridM = (m + TPB - 1) / TPB;
  const int gridN = (N + TPB - 1) / TPB;
  const int gridG = ((size_t)N * Q + TPB - 1) / TPB;   // 8-thread group per node
  const int gridS = min(512, gridM);
  const int nb    = (N4 + SCAN_T - 1) / SCAN_T;

  const float entc  = (float)(4.0 * log(0.5) / log(1.0 / (double)Q));
  const float inv_m = (float)(1.0 / (double)m);
  const float inv_N = (float)(1.0 / (double)N);
  const float omw   = (float)(1.0 - mean_w);

  hipMemsetAsync(cnt4, 0, (size_t)N4 * sizeof(int), stream);
  hipMemsetAsync(S, 0, (size_t)(11 * Q + 3) * sizeof(float), stream);

  // CSR build with 4-way sub-counters
  k_count_pos<<<gridC, TPB, 0, stream>>>(dst, cnt4, pos, E);
  k_scan1<<<nb, SCAN_T, 0, stream>>>(cnt4, rp4, bsum, N4);
  k_scan2<<<1, SCAN_T, 0, stream>>>(bsum, boffs, row_ptr, nb, N);
  k_scan3<<<nb, SCAN_T, 0, stream>>>(rp4, row_ptr, boffs, N4);
  k_build<<<gridM, TPB, 0, stream>>>(src, dst, pos, rp4, msg_init, beta, rn, tA, m);
  k_pi0<<<gridG, TPB, 0, stream>>>(row_ptr, tA, pi0, N);
  k_init_nodes<<<gridN, TPB, 0, stream>>>(psi_init, S, N);

  // 9 deferred-normalization iterations
  __half* tcur = tA; __half* tnxt = tB;
  float*  pcur = pi0; float* pnxt = pi1;
  for (int t = 0; t < 9; ++t) {
    k_iter3<<<gridG, TPB, 0, stream>>>(row_ptr, rn, tcur, tnxt, pcur, pnxt,
                                       beta, S + t * Q, S + (t + 1) * Q,
                                       neg_mw, N, (t < 8) ? 1 : 0);
    __half* th = tcur; tcur = tnxt; tnxt = th;
    float*  pf = pcur; pcur = pnxt; pnxt = pf;
  }

  // psi_10 = normalize(pi_9 * e^{h_9}), entropy fused
  k_psi_ent<<<gridN, TPB, 0, stream>>>(pcur, beta, S + 9 * Q, neg_mw, out, H_acc, N);
  k_edge_stats<<<gridS, TPB, 0, stream>>>(out, src, dst, reg_acc, mod_acc, omw, m);
  k_finalize<<<1, 1, 0, stream>>>(H_acc, reg_acc, mod_acc, out + (size_t)N * Q,
                                  inv_m, inv_N, entc);
}